// Round 1
// 864.107 us; speedup vs baseline: 1.0695x; 1.0695x over previous
//
#include <hip/hip_runtime.h>
#include <cstddef>

typedef __bf16 bf16x8 __attribute__((ext_vector_type(8)));
typedef unsigned short u16x8 __attribute__((ext_vector_type(8)));
typedef float f32x4 __attribute__((ext_vector_type(4)));

#define B_N 8192
#define M_N 50
#define R_N (B_N * M_N)   // 409600
#define P_OFF ((size_t)B_N * 256)
#define V_OFF ((size_t)B_N * 256 + (size_t)B_N * 50)

__device__ __forceinline__ float bf2f(unsigned short u) {
  return __uint_as_float(((unsigned int)u) << 16);
}
__device__ __forceinline__ unsigned short f2bf(float f) {
  unsigned int u = __float_as_uint(f);
  u += 0x7fffu + ((u >> 16) & 1u);
  return (unsigned short)(u >> 16);
}
__device__ __forceinline__ float fsig(float x) { return 1.f / (1.f + __expf(-x)); }
__device__ __forceinline__ float ftanh(float x) {
  float e = __expf(2.f * x);
  return 1.f - 2.f / (e + 1.f);
}

// scalar adaptive load of external input
__device__ __forceinline__ float ld_ext(const void* p, size_t i, bool f32) {
  return f32 ? ((const float*)p)[i] : bf2f(((const unsigned short*)p)[i]);
}
// 8-element adaptive load -> 8 bf16 at dst (16B aligned), i % 8 == 0
__device__ __forceinline__ void ld8_ext(unsigned short* dst, const void* p, size_t i, bool f32) {
  if (f32) {
    const float* fp = (const float*)p + i;
    const float4 a = *(const float4*)fp;
    const float4 b = *(const float4*)(fp + 4);
    u16x8 t;
    t[0] = f2bf(a.x); t[1] = f2bf(a.y); t[2] = f2bf(a.z); t[3] = f2bf(a.w);
    t[4] = f2bf(b.x); t[5] = f2bf(b.y); t[6] = f2bf(b.z); t[7] = f2bf(b.w);
    *(u16x8*)dst = t;
  } else {
    *(uint4*)dst = *(const uint4*)((const unsigned short*)p + i);
  }
}

// async global -> LDS, 16 bytes per lane; lds dest is wave-uniform base + lane*16
__device__ __forceinline__ void gload_lds16(const void* g, void* l) {
  __builtin_amdgcn_global_load_lds(
      (const __attribute__((address_space(1))) unsigned int*)g,
      (__attribute__((address_space(3))) unsigned int*)l, 16, 0, 0);
}

// XOR bank swizzle (involution): spreads 64B-stride rows across all 8 16B bank
// groups -> ds_read_b128 at row-stride 64B becomes 2-way (free, m136).
__device__ __forceinline__ unsigned swz(unsigned b) {
  return b ^ (((b >> 7) & 7u) << 4);
}

// ---------------- dtype probe on X ----------------
__global__ void probe_dtype(const void* __restrict__ X, int* __restrict__ flag) {
  const int lane = threadIdx.x;  // 64 threads
  const unsigned short u = ((const unsigned short*)X)[lane * 2];
  const int e = (u >> 7) & 0xff;
  const bool plausible = (e >= 110 && e <= 144) || (u == 0);
  const unsigned long long m = __ballot(plausible);
  if (lane == 0) *flag = (__popcll(m) < 32) ? 1 : 0;  // 1 => f32 inputs
}

// ---------------- weight transpose: W[K,256] -> WT[256,K] bf16 ----------------
struct TJobs {
  const void* src[15];
  unsigned short* dst[15];
  int K[15];
};

__global__ __launch_bounds__(256) void transpose_weights(TJobs jobs, const int* __restrict__ flagp) {
  const bool f32 = *flagp != 0;
  const int z = blockIdx.z;
  const void* __restrict__ src = jobs.src[z];
  unsigned short* __restrict__ dst = jobs.dst[z];
  const int K = jobs.K[z];
  const int k0 = blockIdx.y * 16;
  if (k0 >= K) return;
  const int n0 = blockIdx.x * 16;
  __shared__ __align__(16) unsigned short tile[16][17];
  const int tx = threadIdx.x & 15, ty = threadIdx.x >> 4;
  const size_t sidx = (size_t)(k0 + ty) * 256 + n0 + tx;
  tile[ty][tx] = f32 ? f2bf(((const float*)src)[sidx]) : ((const unsigned short*)src)[sidx];
  __syncthreads();
  dst[(size_t)(n0 + ty) * K + k0 + tx] = tile[tx][ty];
}

// ---------------- generic small GEMM: bf16 out = act(sum_p A_p @ W_p^T + bias + add) ----------------
struct GJob {
  const void* A[3];             // [8192, K_p] row-major
  const unsigned short* Wt[3];  // [256, K_p] bf16 transposed weight (internal)
  int K[3];                     // 0 terminates
  int atag[3];                  // 0 = internal bf16, 1 = always f32, 2 = external (follow flag)
  const void* bias;             // [256] external or null
  const unsigned short* add;    // [8192,256] bf16 internal or null
  unsigned short* out;          // [8192,256] bf16 internal
  int act;                      // 0 none, 1 sigmoid, 2 tanh
};
struct GJobs { GJob j[4]; };

__global__ __launch_bounds__(256) void gemm_small(GJobs jobs, const int* __restrict__ flagp) {
  const bool flag32 = *flagp != 0;
  const GJob job = jobs.j[blockIdx.z];
  const int tid = threadIdx.x;
  const int row0 = blockIdx.x * 64;
  const int col0 = blockIdx.y * 128;
  __shared__ __align__(16) unsigned short As[64][40];
  __shared__ __align__(16) unsigned short Ws[128][40];

  f32x4 acc[2][4];
#pragma unroll
  for (int i = 0; i < 2; ++i)
#pragma unroll
    for (int j = 0; j < 4; ++j) acc[i][j] = (f32x4){0.f, 0.f, 0.f, 0.f};

  const int wave = tid >> 6, lane = tid & 63;
  const int wr = wave >> 1, wc = wave & 1;
  const int quad = lane >> 4, l16 = lane & 15;

  for (int p = 0; p < 3; ++p) {
    const int Kp = job.K[p];
    if (Kp == 0) break;
    const void* __restrict__ Ap = job.A[p];
    const unsigned short* __restrict__ Wp = job.Wt[p];
    const bool af32 = (job.atag[p] == 1) || (job.atag[p] == 2 && flag32);
    for (int k0 = 0; k0 < Kp; k0 += 32) {
      {
        const int r = tid >> 2, c = (tid & 3) * 8;
        ld8_ext(&As[r][c], Ap, (size_t)(row0 + r) * Kp + k0 + c, af32);
      }
      for (int i = tid; i < 512; i += 256) {
        const int r = i >> 2, c = (i & 3) * 8;
        *(uint4*)&Ws[r][c] = *(const uint4*)&Wp[(size_t)(col0 + r) * Kp + k0 + c];
      }
      __syncthreads();
      bf16x8 af[2], bfr[4];
#pragma unroll
      for (int mi = 0; mi < 2; ++mi)
        af[mi] = *(const bf16x8*)&As[wr * 32 + mi * 16 + l16][quad * 8];
#pragma unroll
      for (int ni = 0; ni < 4; ++ni)
        bfr[ni] = *(const bf16x8*)&Ws[wc * 64 + ni * 16 + l16][quad * 8];
#pragma unroll
      for (int mi = 0; mi < 2; ++mi)
#pragma unroll
        for (int ni = 0; ni < 4; ++ni)
          acc[mi][ni] = __builtin_amdgcn_mfma_f32_16x16x32_bf16(af[mi], bfr[ni], acc[mi][ni], 0, 0, 0);
      __syncthreads();
    }
  }

#pragma unroll
  for (int mi = 0; mi < 2; ++mi) {
#pragma unroll
    for (int ni = 0; ni < 4; ++ni) {
      const int col = col0 + wc * 64 + ni * 16 + l16;
      const float bias = job.bias ? ld_ext(job.bias, col, flag32) : 0.f;
      const int rowb = row0 + wr * 32 + mi * 16 + quad * 4;
#pragma unroll
      for (int r = 0; r < 4; ++r) {
        float v = acc[mi][ni][r] + bias;
        const size_t idx = (size_t)(rowb + r) * 256 + col;
        if (job.add) v += bf2f(job.add[idx]);
        if (job.act == 1) v = fsig(v);
        else if (job.act == 2) v = ftanh(v);
        job.out[idx] = f2bf(v);
      }
    }
  }
}

// ---------------- attention scores (128x256 tile, 8 waves, global_load_lds + swizzle) ----------------
__global__ __launch_bounds__(512, 4) void attn_scores(
    const void* __restrict__ S,
    const unsigned short* __restrict__ WsaT,
    const unsigned short* __restrict__ hWa,   // bf16 [8192,256]
    const void* __restrict__ v_a,
    float* __restrict__ scores,
    const int* __restrict__ flagp) {
  const bool f32 = *flagp != 0;
  const int tid = threadIdx.x;
  const int r0 = blockIdx.x * 128;

  // logical layouts: As [128 rows][32 k] bf16 (row stride 64B), Ws [256 cols][32 k].
  // physical byte offset = swz(logical byte offset); global_load_lds writes the
  // linear physical order, so the SOURCE address is pre-swizzled (rule: both-sides).
  __shared__ __align__(128) unsigned short As[128 * 32];   //  8 KB
  __shared__ __align__(128) unsigned short Ws[256 * 32];   // 16 KB
  __shared__ float hWs[4][256];
  __shared__ float vas[256];
  __shared__ __align__(16) float red[128][4];

  const int wave = tid >> 6, lane = tid & 63;
  const int wr = wave >> 2, wc = wave & 3;     // 2 x 4 wave grid
  const int quad = lane >> 4, l16 = lane & 15;

  const int b_first = r0 / 50;
  for (int i = tid; i < 1024; i += 512) {
    const int j = i >> 8, u = i & 255;
    const int b = b_first + j;
    hWs[j][u] = (b < B_N) ? bf2f(hWa[(size_t)b * 256 + u]) : 0.f;
  }
  if (tid < 256) vas[tid] = ld_ext(v_a, tid, f32);

  f32x4 acc[4][4];
#pragma unroll
  for (int i = 0; i < 4; ++i)
#pragma unroll
    for (int j = 0; j < 4; ++j) acc[i][j] = (f32x4){0.f, 0.f, 0.f, 0.f};

  // staging geometry: thread covers physical 16B chunk at o; data for it comes
  // from the logical chunk l = swz(o).
  const unsigned oA = tid * 16;
  const unsigned lA = swz(oA);
  const unsigned rowA = lA >> 6, slA = (lA >> 4) & 3;
  const size_t gAbase = (size_t)(r0 + rowA) * 256 + slA * 8;  // + k0
  char* const ldsA = (char*)As + (wave << 10);

  const unsigned lW0 = swz(tid * 16);
  const unsigned rowW0 = lW0 >> 6, slW0 = (lW0 >> 4) & 3;
  const unsigned lW1 = swz((tid + 512) * 16);
  const unsigned rowW1 = lW1 >> 6, slW1 = (lW1 >> 4) & 3;
  char* const ldsW0 = (char*)Ws + (wave << 10);
  char* const ldsW1 = (char*)Ws + 8192 + (wave << 10);

  for (int k0 = 0; k0 < 256; k0 += 32) {
    if (f32) {
      const float* fp = (const float*)S + gAbase + k0;
      const float4 a = *(const float4*)fp;
      const float4 b = *(const float4*)(fp + 4);
      u16x8 t;
      t[0] = f2bf(a.x); t[1] = f2bf(a.y); t[2] = f2bf(a.z); t[3] = f2bf(a.w);
      t[4] = f2bf(b.x); t[5] = f2bf(b.y); t[6] = f2bf(b.z); t[7] = f2bf(b.w);
      *(u16x8*)((char*)As + oA) = t;
    } else {
      gload_lds16((const unsigned short*)S + gAbase + k0, ldsA);
    }
    gload_lds16(WsaT + (size_t)rowW0 * 256 + k0 + slW0 * 8, ldsW0);
    gload_lds16(WsaT + (size_t)rowW1 * 256 + k0 + slW1 * 8, ldsW1);
    __syncthreads();

    bf16x8 af[4], bfr[4];
#pragma unroll
    for (int mi = 0; mi < 4; ++mi) {
      const unsigned lb = (unsigned)(wr * 64 + mi * 16 + l16) * 64 + quad * 16;
      af[mi] = *(const bf16x8*)((const char*)As + swz(lb));
    }
#pragma unroll
    for (int ni = 0; ni < 4; ++ni) {
      const unsigned lb = (unsigned)(wc * 64 + ni * 16 + l16) * 64 + quad * 16;
      bfr[ni] = *(const bf16x8*)((const char*)Ws + swz(lb));
    }
#pragma unroll
    for (int mi = 0; mi < 4; ++mi)
#pragma unroll
      for (int ni = 0; ni < 4; ++ni)
        acc[mi][ni] = __builtin_amdgcn_mfma_f32_16x16x32_bf16(af[mi], bfr[ni], acc[mi][ni], 0, 0, 0);
    __syncthreads();
  }

  // epilogue: ps[row] = sum_col tanh(acc + hW) * v_a
  float ps[4][4];
#pragma unroll
  for (int mi = 0; mi < 4; ++mi) {
#pragma unroll
    for (int r = 0; r < 4; ++r) {
      const int rl = wr * 64 + mi * 16 + quad * 4 + r;
      const int bj = (r0 + rl) / 50 - b_first;
      float s = 0.f;
#pragma unroll
      for (int ni = 0; ni < 4; ++ni) {
        const int col = wc * 64 + ni * 16 + l16;
        s += ftanh(acc[mi][ni][r] + hWs[bj][col]) * vas[col];
      }
      ps[mi][r] = s;
    }
  }
#pragma unroll
  for (int mi = 0; mi < 4; ++mi)
#pragma unroll
    for (int r = 0; r < 4; ++r) {
      float v = ps[mi][r];
      v += __shfl_xor(v, 1);
      v += __shfl_xor(v, 2);
      v += __shfl_xor(v, 4);
      v += __shfl_xor(v, 8);
      if (l16 == 0) red[wr * 64 + mi * 16 + quad * 4 + r][wc] = v;
    }
  __syncthreads();
  if (tid < 128) {
    const float4 rr = *(const float4*)&red[tid][0];
    scores[r0 + tid] = rr.x + rr.y + rr.z + rr.w;
  }
}

// ---------------- fused softmax (M=50) + text = P . S ----------------
__global__ __launch_bounds__(256) void softmax_text(
    const float* __restrict__ scores,
    const void* __restrict__ S,
    float* __restrict__ out,               // fp32 output base
    unsigned short* __restrict__ text,     // internal bf16
    const int* __restrict__ flagp) {
  const bool f32 = *flagp != 0;
  const int tid = threadIdx.x;
  const int wave = tid >> 6, lane = tid & 63;
  const int b = blockIdx.x * 4 + wave;
  __shared__ float Pl[4][64];

  float s = (lane < 50) ? scores[(size_t)b * 50 + lane] : -1e30f;
  float mx = s;
#pragma unroll
  for (int off = 32; off > 0; off >>= 1) mx = fmaxf(mx, __shfl_xor(mx, off));
  float e = (lane < 50) ? __expf(s - mx) : 0.f;
  float sum = e;
#pragma unroll
  for (int off = 32; off > 0; off >>= 1) sum += __shfl_xor(sum, off);
  const float p = e / sum;
  if (lane < 50) out[P_OFF + (size_t)b * 50 + lane] = p;
  Pl[wave][lane] = p;
  __syncthreads();

  float a0 = 0.f, a1 = 0.f, a2 = 0.f, a3 = 0.f;
  const size_t base = (size_t)b * 50 * 256 + lane * 4;
  for (int m = 0; m < 50; ++m) {
    const float pm = Pl[wave][m];
    const size_t ix = base + (size_t)m * 256;
    float s0, s1, s2, s3;
    if (f32) {
      const float4 sv = *(const float4*)((const float*)S + ix);
      s0 = sv.x; s1 = sv.y; s2 = sv.z; s3 = sv.w;
    } else {
      const uint2 raw = *(const uint2*)((const unsigned short*)S + ix);
      s0 = bf2f((unsigned short)(raw.x & 0xffffu));
      s1 = bf2f((unsigned short)(raw.x >> 16));
      s2 = bf2f((unsigned short)(raw.y & 0xffffu));
      s3 = bf2f((unsigned short)(raw.y >> 16));
    }
    a0 += pm * s0; a1 += pm * s1; a2 += pm * s2; a3 += pm * s3;
  }
  uint2 o;
  o.x = (unsigned int)f2bf(a0) | ((unsigned int)f2bf(a1) << 16);
  o.y = (unsigned int)f2bf(a2) | ((unsigned int)f2bf(a3) << 16);
  *(uint2*)&text[(size_t)b * 256 + lane * 4] = o;
}

// ---------------- V = F*v + O*T  (fp32 to d_out) ----------------
__global__ __launch_bounds__(256) void v_combine(
    const unsigned short* __restrict__ F, const unsigned short* __restrict__ O,
    const unsigned short* __restrict__ T,
    const void* __restrict__ v, float* __restrict__ out,
    const int* __restrict__ flagp) {
  const bool f32 = *flagp != 0;
  const int i = (blockIdx.x * 256 + threadIdx.x) * 4;
  float v0, v1, v2, v3;
  if (f32) {
    const float4 vv = *(const float4*)((const float*)v + i);
    v0 = vv.x; v1 = vv.y; v2 = vv.z; v3 = vv.w;
  } else {
    const uint2 vr = *(const uint2*)((const unsigned short*)v + i);
    v0 = bf2f((unsigned short)(vr.x & 0xffffu));
    v1 = bf2f((unsigned short)(vr.x >> 16));
    v2 = bf2f((unsigned short)(vr.y & 0xffffu));
    v3 = bf2f((unsigned short)(vr.y >> 16));
  }
  const uint2 Fr = *(const uint2*)&F[i];
  const uint2 Or = *(const uint2*)&O[i];
  const uint2 Tr = *(const uint2*)&T[i];
  float4 o;
  o.x = bf2f((unsigned short)(Fr.x & 0xffffu)) * v0 + bf2f((unsigned short)(Or.x & 0xffffu)) * bf2f((unsigned short)(Tr.x & 0xffffu));
  o.y = bf2f((unsigned short)(Fr.x >> 16))     * v1 + bf2f((unsigned short)(Or.x >> 16))     * bf2f((unsigned short)(Tr.x >> 16));
  o.z = bf2f((unsigned short)(Fr.y & 0xffffu)) * v2 + bf2f((unsigned short)(Or.y & 0xffffu)) * bf2f((unsigned short)(Tr.y & 0xffffu));
  o.w = bf2f((unsigned short)(Fr.y >> 16))     * v3 + bf2f((unsigned short)(Or.y >> 16))     * bf2f((unsigned short)(Tr.y >> 16));
  *(float4*)&out[V_OFF + i] = o;
}

// ---------------- H = (1-k)*hv + k*hx  (fp32 to d_out) ----------------
__global__ __launch_bounds__(256) void h_combine(
    const unsigned short* __restrict__ kk, const unsigned short* __restrict__ hv,
    const unsigned short* __restrict__ hx, float* __restrict__ Hout) {
  const int i = (blockIdx.x * 256 + threadIdx.x) * 4;
  const uint2 kr = *(const uint2*)&kk[i];
  const uint2 vr = *(const uint2*)&hv[i];
  const uint2 xr = *(const uint2*)&hx[i];
  const float k0 = bf2f((unsigned short)(kr.x & 0xffffu)), k1 = bf2f((unsigned short)(kr.x >> 16));
  const float k2 = bf2f((unsigned short)(kr.y & 0xffffu)), k3 = bf2f((unsigned short)(kr.y >> 16));
  const float hv0 = bf2f((unsigned short)(vr.x & 0xffffu)), hv1 = bf2f((unsigned short)(vr.x >> 16));
  const float hv2 = bf2f((unsigned short)(vr.y & 0xffffu)), hv3 = bf2f((unsigned short)(vr.y >> 16));
  const float hx0 = bf2f((unsigned short)(xr.x & 0xffffu)), hx1 = bf2f((unsigned short)(xr.x >> 16));
  const float hx2 = bf2f((unsigned short)(xr.y & 0xffffu)), hx3 = bf2f((unsigned short)(xr.y >> 16));
  float4 o;
  o.x = (1.f - k0) * hv0 + k0 * hx0;
  o.y = (1.f - k1) * hv1 + k1 * hx1;
  o.z = (1.f - k2) * hv2 + k2 * hx2;
  o.w = (1.f - k3) * hv3 + k3 * hx3;
  *(float4*)&Hout[i] = o;
}

extern "C" void kernel_launch(void* const* d_in, const int* in_sizes, int n_in,
                              void* d_out, int out_size, void* d_ws, size_t ws_size,
                              hipStream_t stream) {
  const void* X   = d_in[0];
  const void* S   = d_in[1];
  const void* h   = d_in[2];
  const void* v   = d_in[3];
  const void* b_a = d_in[6];
  const void* v_a = d_in[7];
  const void* b_f = d_in[10];
  const void* b_o = d_in[13];
  const void* b_t = d_in[16];
  const void* b_k = d_in[20];
  const void* b_s = d_in[23];
  const void* b_v = d_in[26];

  float* out = (float*)d_out;  // fp32 output (H | P | V)
  float* out_V = out + V_OFF;

  char* ws = (char*)d_ws;
  int* flag = (int*)ws;
  size_t off = 256;

  const int widx[15] = {4, 5, 8, 9, 11, 12, 14, 15, 17, 18, 19, 21, 22, 24, 25};
  const int wK[15]   = {256, 256, 256, 256, 256, 256, 256, 256, 512, 256, 256, 512, 256, 256, 256};
  TJobs tj;
  unsigned short* wt[15];
  for (int i = 0; i < 15; ++i) {
    wt[i] = (unsigned short*)(ws + off);
    off += (size_t)wK[i] * 256 * 2;
    tj.src[i] = d_in[widx[i]];
    tj.dst[i] = wt[i];
    tj.K[i] = wK[i];
  }
  const unsigned short *WsaT = wt[0], *WhaT = wt[1], *WfT = wt[2], *WhfT = wt[3],
                       *WoT = wt[4], *WhoT = wt[5], *WtT = wt[6], *WhtT = wt[7],
                       *WkT = wt[8], *WhkT = wt[9], *WvkT = wt[10], *WsT = wt[11],
                       *WhsT = wt[12], *WvT = wt[13], *WhvT = wt[14];
  off = (off + 255) & ~(size_t)255;
  const size_t BS = (size_t)B_N * 256 * 2;  // bf16 [8192,256] = 4 MB
  unsigned short* hWa   = (unsigned short*)(ws + off); off += BS;
  float* scores         = (float*)(ws + off);          off += (size_t)R_N * sizeof(float);
  unsigned short* text  = (unsigned short*)(ws + off); off += BS;
  unsigned short* Fb    = (unsigned short*)(ws + off); off += BS;
  unsigned short* Ob    = (unsigned short*)(ws + off); off += BS;
  unsigned short* Tb    = (unsigned short*)(ws + off); off += BS;
  unsigned short* kpre  = (unsigned short*)(ws + off); off += BS;
  unsigned short* hx    = (unsigned short*)(ws + off); off += BS;
  unsigned short* hvpre = (unsigned short*)(ws + off); off += BS;

  probe_dtype<<<1, 64, 0, stream>>>(X, flag);
  transpose_weights<<<dim3(16, 32, 15), 256, 0, stream>>>(tj, flag);

  // Launch A: hWa, kpre, hx, hvpre
  GJobs jA;
  for (int i = 0; i < 4; ++i) jA.j[i] = GJob{};
  jA.j[0].A[0] = h;  jA.j[0].atag[0] = 2; jA.j[0].Wt[0] = WhaT; jA.j[0].K[0] = 256;
  jA.j[0].bias = b_a; jA.j[0].out = hWa; jA.j[0].act = 0;
  jA.j[1].A[0] = X;  jA.j[1].atag[0] = 2; jA.j[1].Wt[0] = WkT;  jA.j[1].K[0] = 512;
  jA.j[1].A[1] = h;  jA.j[1].atag[1] = 2; jA.j[1].Wt[1] = WhkT; jA.j[1].K[1] = 256;
  jA.j[1].bias = b_k; jA.j[1].out = kpre; jA.j[1].act = 0;
  jA.j[2].A[0] = X;  jA.j[2].atag[0] = 2; jA.j[2].Wt[0] = WsT;  jA.j[2].K[0] = 512;
  jA.j[2].A[1] = h;  jA.j[2].atag[1] = 2; jA.j[2].Wt[1] = WhsT; jA.j[2].K[1] = 256;
  jA.j[2].bias = b_s; jA.j[2].out = hx; jA.j[2].act = 2;
  jA.j[3].A[0] = h;  jA.j[3].atag[0] = 2; jA.j[3].Wt[0] = WhvT; jA.j[3].K[0] = 256;
  jA.j[3].bias = b_v; jA.j[3].out = hvpre; jA.j[3].act = 0;
  gemm_small<<<dim3(128, 2, 4), 256, 0, stream>>>(jA, flag);

  attn_scores<<<dim3(R_N / 128), 512, 0, stream>>>(S, WsaT, hWa, v_a, scores, flag);
  softmax_text<<<dim3(B_N / 4), 256, 0, stream>>>(scores, S, out, text, flag);

  // Launch B: F, O, T
  GJobs jB;
  for (int i = 0; i < 4; ++i) jB.j[i] = GJob{};
  jB.j[0].A[0] = text; jB.j[0].atag[0] = 0; jB.j[0].Wt[0] = WfT;  jB.j[0].K[0] = 256;
  jB.j[0].A[1] = h;    jB.j[0].atag[1] = 2; jB.j[0].Wt[1] = WhfT; jB.j[0].K[1] = 256;
  jB.j[0].bias = b_f; jB.j[0].out = Fb; jB.j[0].act = 1;
  jB.j[1].A[0] = text; jB.j[1].atag[0] = 0; jB.j[1].Wt[0] = WoT;  jB.j[1].K[0] = 256;
  jB.j[1].A[1] = h;    jB.j[1].atag[1] = 2; jB.j[1].Wt[1] = WhoT; jB.j[1].K[1] = 256;
  jB.j[1].bias = b_o; jB.j[1].out = Ob; jB.j[1].act = 1;
  jB.j[2].A[0] = text; jB.j[2].atag[0] = 0; jB.j[2].Wt[0] = WtT;  jB.j[2].K[0] = 256;
  jB.j[2].A[1] = h;    jB.j[2].atag[1] = 2; jB.j[2].Wt[1] = WhtT; jB.j[2].K[1] = 256;
  jB.j[2].bias = b_t; jB.j[2].out = Tb; jB.j[2].act = 2;
  gemm_small<<<dim3(128, 2, 3), 256, 0, stream>>>(jB, flag);

  v_combine<<<dim3(B_N * 256 / 1024), 256, 0, stream>>>(Fb, Ob, Tb, v, out, flag);

  // Launch C: k = sigmoid(V@W_vk + kpre), hv = tanh(V@W_v + hvpre); V is fp32 in d_out
  GJobs jC;
  for (int i = 0; i < 4; ++i) jC.j[i] = GJob{};
  jC.j[0].A[0] = out_V; jC.j[0].atag[0] = 1; jC.j[0].Wt[0] = WvkT; jC.j[0].K[0] = 256;
  jC.j[0].add = kpre; jC.j[0].out = kpre; jC.j[0].act = 1;
  jC.j[1].A[0] = out_V; jC.j[1].atag[0] = 1; jC.j[1].Wt[0] = WvT;  jC.j[1].K[0] = 256;
  jC.j[1].add = hvpre; jC.j[1].out = hvpre; jC.j[1].act = 2;
  gemm_small<<<dim3(128, 2, 2), 256, 0, stream>>>(jC, flag);

  h_combine<<<dim3(B_N * 256 / 1024), 256, 0, stream>>>(kpre, hvpre, hx, out);
}

// Round 2
// 863.534 us; speedup vs baseline: 1.0702x; 1.0007x over previous
//
#include <hip/hip_runtime.h>
#include <cstddef>

typedef __bf16 bf16x8 __attribute__((ext_vector_type(8)));
typedef unsigned short u16x8 __attribute__((ext_vector_type(8)));
typedef float f32x4 __attribute__((ext_vector_type(4)));

#define B_N 8192
#define M_N 50
#define R_N (B_N * M_N)   // 409600
#define P_OFF ((size_t)B_N * 256)
#define V_OFF ((size_t)B_N * 256 + (size_t)B_N * 50)

__device__ __forceinline__ float bf2f(unsigned short u) {
  return __uint_as_float(((unsigned int)u) << 16);
}
__device__ __forceinline__ unsigned short f2bf(float f) {
  unsigned int u = __float_as_uint(f);
  u += 0x7fffu + ((u >> 16) & 1u);
  return (unsigned short)(u >> 16);
}
__device__ __forceinline__ float fsig(float x) { return 1.f / (1.f + __expf(-x)); }
__device__ __forceinline__ float ftanh(float x) {
  float e = __expf(2.f * x);
  return 1.f - 2.f / (e + 1.f);
}

// scalar adaptive load of external input
__device__ __forceinline__ float ld_ext(const void* p, size_t i, bool f32) {
  return f32 ? ((const float*)p)[i] : bf2f(((const unsigned short*)p)[i]);
}

// async global -> LDS, 16 bytes per lane; lds dest is wave-uniform base + lane*16
__device__ __forceinline__ void gload_lds16(const void* g, void* l) {
  __builtin_amdgcn_global_load_lds(
      (const __attribute__((address_space(1))) unsigned int*)g,
      (__attribute__((address_space(3))) unsigned int*)l, 16, 0, 0);
}

// XOR bank swizzle (involution): spreads 64B-stride rows across all 8 16B bank
// groups -> ds_read_b128 at row-stride 64B becomes 2-way (free, m136).
__device__ __forceinline__ unsigned swz(unsigned b) {
  return b ^ (((b >> 7) & 7u) << 4);
}

// ---------------- dtype probe on X ----------------
__global__ void probe_dtype(const void* __restrict__ X, int* __restrict__ flag) {
  const int lane = threadIdx.x;  // 64 threads
  const unsigned short u = ((const unsigned short*)X)[lane * 2];
  const int e = (u >> 7) & 0xff;
  const bool plausible = (e >= 110 && e <= 144) || (u == 0);
  const unsigned long long m = __ballot(plausible);
  if (lane == 0) *flag = (__popcll(m) < 32) ? 1 : 0;  // 1 => f32 inputs
}

// ---------------- weight transpose: W[K,256] -> WT[256,K] bf16 ----------------
struct TJobs {
  const void* src[15];
  unsigned short* dst[15];
  int K[15];
};

__global__ __launch_bounds__(256) void transpose_weights(TJobs jobs, const int* __restrict__ flagp) {
  const bool f32 = *flagp != 0;
  const int z = blockIdx.z;
  const void* __restrict__ src = jobs.src[z];
  unsigned short* __restrict__ dst = jobs.dst[z];
  const int K = jobs.K[z];
  const int k0 = blockIdx.y * 16;
  if (k0 >= K) return;
  const int n0 = blockIdx.x * 16;
  __shared__ __align__(16) unsigned short tile[16][17];
  const int tx = threadIdx.x & 15, ty = threadIdx.x >> 4;
  const size_t sidx = (size_t)(k0 + ty) * 256 + n0 + tx;
  tile[ty][tx] = f32 ? f2bf(((const float*)src)[sidx]) : ((const unsigned short*)src)[sidx];
  __syncthreads();
  dst[(size_t)(n0 + ty) * K + k0 + tx] = tile[tx][ty];
}

// ---------------- generic small GEMM (2-phase pipelined) ----------------
struct GJob {
  const void* A[3];             // [8192, K_p] row-major
  const unsigned short* Wt[3];  // [256, K_p] bf16 transposed weight (internal)
  int K[3];                     // 0 terminates
  int atag[3];                  // 0 = internal bf16, 1 = always f32, 2 = external (follow flag)
  const void* bias;             // [256] external or null
  const unsigned short* add;    // [8192,256] bf16 internal or null
  unsigned short* out;          // [8192,256] bf16 internal
  int act;                      // 0 none, 1 sigmoid, 2 tanh
};
struct GJobs { GJob j[4]; };

__global__ __launch_bounds__(256) void gemm_small(GJobs jobs, const int* __restrict__ flagp) {
  const bool flag32 = *flagp != 0;
  const GJob job = jobs.j[blockIdx.z];
  const int tid = threadIdx.x;
  const int row0 = blockIdx.x * 64;
  const int col0 = blockIdx.y * 128;
  __shared__ __align__(16) unsigned short As[2][64][40];
  __shared__ __align__(16) unsigned short Ws[2][128][40];

  f32x4 acc[2][4];
#pragma unroll
  for (int i = 0; i < 2; ++i)
#pragma unroll
    for (int j = 0; j < 4; ++j) acc[i][j] = (f32x4){0.f, 0.f, 0.f, 0.f};

  const int wave = tid >> 6, lane = tid & 63;
  const int wr = wave >> 1, wc = wave & 1;
  const int quad = lane >> 4, l16 = lane & 15;

  // flatten segments
  const void* Aseg[3]; const unsigned short* Wseg[3]; int Kseg[3]; bool Fseg[3];
  int nseg = 0, nt = 0, sbeg[4];
  sbeg[0] = 0;
  for (int p = 0; p < 3; ++p) {
    if (job.K[p] == 0) break;
    Aseg[nseg] = job.A[p]; Wseg[nseg] = job.Wt[p]; Kseg[nseg] = job.K[p];
    Fseg[nseg] = (job.atag[p] == 1) || (job.atag[p] == 2 && flag32);
    nt += job.K[p] / 32;
    ++nseg; sbeg[nseg] = nt;
  }

  const int rA = tid >> 2, cA = (tid & 3) * 8;   // A chunk: row rA, col cA (8 elem)
  const int rW = tid >> 2, cW = (tid & 3) * 8;   // W chunks: rows rW and rW+64

  uint4 pa, pw0, pw1;
  float4 fa, fb;
  bool pf32 = false;

  auto issue = [&](int t) {
    int s = 0;
    while (t >= sbeg[s + 1]) ++s;
    const int k0 = (t - sbeg[s]) * 32;
    const int Kp = Kseg[s];
    pf32 = Fseg[s];
    if (pf32) {
      const float* fp = (const float*)Aseg[s] + (size_t)(row0 + rA) * Kp + k0 + cA;
      fa = *(const float4*)fp;
      fb = *(const float4*)(fp + 4);
    } else {
      pa = *(const uint4*)((const unsigned short*)Aseg[s] + (size_t)(row0 + rA) * Kp + k0 + cA);
    }
    pw0 = *(const uint4*)&Wseg[s][(size_t)(col0 + rW) * Kp + k0 + cW];
    pw1 = *(const uint4*)&Wseg[s][(size_t)(col0 + rW + 64) * Kp + k0 + cW];
  };
  auto commit = [&](int buf) {
    if (pf32) {
      u16x8 v;
      v[0] = f2bf(fa.x); v[1] = f2bf(fa.y); v[2] = f2bf(fa.z); v[3] = f2bf(fa.w);
      v[4] = f2bf(fb.x); v[5] = f2bf(fb.y); v[6] = f2bf(fb.z); v[7] = f2bf(fb.w);
      *(u16x8*)&As[buf][rA][cA] = v;
    } else {
      *(uint4*)&As[buf][rA][cA] = pa;
    }
    *(uint4*)&Ws[buf][rW][cW] = pw0;
    *(uint4*)&Ws[buf][rW + 64][cW] = pw1;
  };

  issue(0);
  commit(0);
  __syncthreads();

  int buf = 0;
  for (int t = 0; t < nt; ++t) {
    if (t + 1 < nt) issue(t + 1);   // global loads for next tile in flight over compute
    bf16x8 af[2], bfr[4];
#pragma unroll
    for (int mi = 0; mi < 2; ++mi)
      af[mi] = *(const bf16x8*)&As[buf][wr * 32 + mi * 16 + l16][quad * 8];
#pragma unroll
    for (int ni = 0; ni < 4; ++ni)
      bfr[ni] = *(const bf16x8*)&Ws[buf][wc * 64 + ni * 16 + l16][quad * 8];
#pragma unroll
    for (int mi = 0; mi < 2; ++mi)
#pragma unroll
      for (int ni = 0; ni < 4; ++ni)
        acc[mi][ni] = __builtin_amdgcn_mfma_f32_16x16x32_bf16(af[mi], bfr[ni], acc[mi][ni], 0, 0, 0);
    if (t + 1 < nt) commit(buf ^ 1);
    __syncthreads();
    buf ^= 1;
  }

#pragma unroll
  for (int mi = 0; mi < 2; ++mi) {
#pragma unroll
    for (int ni = 0; ni < 4; ++ni) {
      const int col = col0 + wc * 64 + ni * 16 + l16;
      const float bias = job.bias ? ld_ext(job.bias, col, flag32) : 0.f;
      const int rowb = row0 + wr * 32 + mi * 16 + quad * 4;
#pragma unroll
      for (int r = 0; r < 4; ++r) {
        float v = acc[mi][ni][r] + bias;
        const size_t idx = (size_t)(rowb + r) * 256 + col;
        if (job.add) v += bf2f(job.add[idx]);
        if (job.act == 1) v = fsig(v);
        else if (job.act == 2) v = ftanh(v);
        job.out[idx] = f2bf(v);
      }
    }
  }
}

// ---------------- attention scores (128x256 tile, 8 waves, 2-phase pipeline) ----------------
__global__ __launch_bounds__(512, 4) void attn_scores(
    const void* __restrict__ S,
    const unsigned short* __restrict__ WsaT,
    const unsigned short* __restrict__ hWa,   // bf16 [8192,256]
    const void* __restrict__ v_a,
    float* __restrict__ scores,
    const int* __restrict__ flagp) {
  const bool f32 = *flagp != 0;
  const int tid = threadIdx.x;
  const int r0 = blockIdx.x * 128;

  // double-buffered tiles; physical byte offset = swz(logical byte offset).
  // global_load_lds writes linear physical order -> SOURCE address pre-swizzled.
  __shared__ __align__(128) unsigned short As[2 * 128 * 32];   // 16 KB
  __shared__ __align__(128) unsigned short Ws[2 * 256 * 32];   // 32 KB
  __shared__ float hWs[4][256];
  __shared__ float vas[256];
  __shared__ __align__(16) float red[128][4];

  const int wave = tid >> 6, lane = tid & 63;
  const int wr = wave >> 2, wc = wave & 3;     // 2 x 4 wave grid
  const int quad = lane >> 4, l16 = lane & 15;

  // staging geometry: thread covers physical 16B chunk at oA within a buffer;
  // data comes from logical chunk swz(oA).
  const unsigned oA = tid * 16;
  const unsigned lA = swz(oA);
  const unsigned rowA = lA >> 6, slA = (lA >> 4) & 3;
  const size_t gAbase = (size_t)(r0 + rowA) * 256 + slA * 8;  // + k0
  // W covers 16 KB per buffer: chunk0 at oA (rows 0..127), chunk1 at oA+8192
  // (rows 128..255); swz(oA+8192) == swz(oA)+8192 since bit 13 doesn't feed the XOR.
  const size_t gWbase0 = (size_t)rowA * 256 + slA * 8;
  const size_t gWbase1 = (size_t)(rowA + 128) * 256 + slA * 8;

  auto stage = [&](int buf, int k0) {
    char* const aDst = (char*)As + buf * 8192 + (wave << 10);
    char* const wDst0 = (char*)Ws + buf * 16384 + (wave << 10);
    char* const wDst1 = wDst0 + 8192;
    if (f32) {
      const float* fp = (const float*)S + gAbase + k0;
      const float4 a = *(const float4*)fp;
      const float4 b = *(const float4*)(fp + 4);
      u16x8 t;
      t[0] = f2bf(a.x); t[1] = f2bf(a.y); t[2] = f2bf(a.z); t[3] = f2bf(a.w);
      t[4] = f2bf(b.x); t[5] = f2bf(b.y); t[6] = f2bf(b.z); t[7] = f2bf(b.w);
      *(u16x8*)((char*)As + buf * 8192 + oA) = t;
    } else {
      gload_lds16((const unsigned short*)S + gAbase + k0, aDst);
    }
    gload_lds16(WsaT + gWbase0 + k0, wDst0);
    gload_lds16(WsaT + gWbase1 + k0, wDst1);
  };

  f32x4 acc[4][4];
#pragma unroll
  for (int i = 0; i < 4; ++i)
#pragma unroll
    for (int j = 0; j < 4; ++j) acc[i][j] = (f32x4){0.f, 0.f, 0.f, 0.f};

  stage(0, 0);
  const int b_first = r0 / 50;
  for (int i = tid; i < 1024; i += 512) {
    const int j = i >> 8, u = i & 255;
    const int b = b_first + j;
    hWs[j][u] = (b < B_N) ? bf2f(hWa[(size_t)b * 256 + u]) : 0.f;
  }
  if (tid < 256) vas[tid] = ld_ext(v_a, tid, f32);
  __syncthreads();

  int buf = 0;
  for (int t = 0; t < 8; ++t) {
    if (t < 7) stage(buf ^ 1, (t + 1) * 32);  // next tile's loads fly over compute
    const char* aB = (const char*)As + buf * 8192;
    const char* wB = (const char*)Ws + buf * 16384;
    bf16x8 af[4], bfr[4];
#pragma unroll
    for (int mi = 0; mi < 4; ++mi) {
      const unsigned lb = (unsigned)(wr * 64 + mi * 16 + l16) * 64 + quad * 16;
      af[mi] = *(const bf16x8*)(aB + swz(lb));
    }
#pragma unroll
    for (int ni = 0; ni < 4; ++ni) {
      const unsigned lb = (unsigned)(wc * 64 + ni * 16 + l16) * 64 + quad * 16;
      bfr[ni] = *(const bf16x8*)(wB + swz(lb));
    }
#pragma unroll
    for (int mi = 0; mi < 4; ++mi)
#pragma unroll
      for (int ni = 0; ni < 4; ++ni)
        acc[mi][ni] = __builtin_amdgcn_mfma_f32_16x16x32_bf16(af[mi], bfr[ni], acc[mi][ni], 0, 0, 0);
    __syncthreads();
    buf ^= 1;
  }

  // epilogue: ps[row] = sum_col tanh(acc + hW) * v_a
  float ps[4][4];
#pragma unroll
  for (int mi = 0; mi < 4; ++mi) {
#pragma unroll
    for (int r = 0; r < 4; ++r) {
      const int rl = wr * 64 + mi * 16 + quad * 4 + r;
      const int bj = (r0 + rl) / 50 - b_first;
      float s = 0.f;
#pragma unroll
      for (int ni = 0; ni < 4; ++ni) {
        const int col = wc * 64 + ni * 16 + l16;
        s += ftanh(acc[mi][ni][r] + hWs[bj][col]) * vas[col];
      }
      ps[mi][r] = s;
    }
  }
#pragma unroll
  for (int mi = 0; mi < 4; ++mi)
#pragma unroll
    for (int r = 0; r < 4; ++r) {
      float v = ps[mi][r];
      v += __shfl_xor(v, 1);
      v += __shfl_xor(v, 2);
      v += __shfl_xor(v, 4);
      v += __shfl_xor(v, 8);
      if (l16 == 0) red[wr * 64 + mi * 16 + quad * 4 + r][wc] = v;
    }
  __syncthreads();
  if (tid < 128) {
    const float4 rr = *(const float4*)&red[tid][0];
    scores[r0 + tid] = rr.x + rr.y + rr.z + rr.w;
  }
}

// ---------------- fused softmax (M=50) + text = P . S ----------------
__global__ __launch_bounds__(256) void softmax_text(
    const float* __restrict__ scores,
    const void* __restrict__ S,
    float* __restrict__ out,               // fp32 output base
    unsigned short* __restrict__ text,     // internal bf16
    const int* __restrict__ flagp) {
  const bool f32 = *flagp != 0;
  const int tid = threadIdx.x;
  const int wave = tid >> 6, lane = tid & 63;
  const int b = blockIdx.x * 4 + wave;
  __shared__ float Pl[4][64];

  float s = (lane < 50) ? scores[(size_t)b * 50 + lane] : -1e30f;
  float mx = s;
#pragma unroll
  for (int off = 32; off > 0; off >>= 1) mx = fmaxf(mx, __shfl_xor(mx, off));
  float e = (lane < 50) ? __expf(s - mx) : 0.f;
  float sum = e;
#pragma unroll
  for (int off = 32; off > 0; off >>= 1) sum += __shfl_xor(sum, off);
  const float p = e / sum;
  if (lane < 50) out[P_OFF + (size_t)b * 50 + lane] = p;
  Pl[wave][lane] = p;
  __syncthreads();

  float a0 = 0.f, a1 = 0.f, a2 = 0.f, a3 = 0.f;
  const size_t base = (size_t)b * 50 * 256 + lane * 4;
  for (int m = 0; m < 50; ++m) {
    const float pm = Pl[wave][m];
    const size_t ix = base + (size_t)m * 256;
    float s0, s1, s2, s3;
    if (f32) {
      const float4 sv = *(const float4*)((const float*)S + ix);
      s0 = sv.x; s1 = sv.y; s2 = sv.z; s3 = sv.w;
    } else {
      const uint2 raw = *(const uint2*)((const unsigned short*)S + ix);
      s0 = bf2f((unsigned short)(raw.x & 0xffffu));
      s1 = bf2f((unsigned short)(raw.x >> 16));
      s2 = bf2f((unsigned short)(raw.y & 0xffffu));
      s3 = bf2f((unsigned short)(raw.y >> 16));
    }
    a0 += pm * s0; a1 += pm * s1; a2 += pm * s2; a3 += pm * s3;
  }
  uint2 o;
  o.x = (unsigned int)f2bf(a0) | ((unsigned int)f2bf(a1) << 16);
  o.y = (unsigned int)f2bf(a2) | ((unsigned int)f2bf(a3) << 16);
  *(uint2*)&text[(size_t)b * 256 + lane * 4] = o;
}

// ---------------- V = F*v + O*T  (fp32 to d_out) ----------------
__global__ __launch_bounds__(256) void v_combine(
    const unsigned short* __restrict__ F, const unsigned short* __restrict__ O,
    const unsigned short* __restrict__ T,
    const void* __restrict__ v, float* __restrict__ out,
    const int* __restrict__ flagp) {
  const bool f32 = *flagp != 0;
  const int i = (blockIdx.x * 256 + threadIdx.x) * 4;
  float v0, v1, v2, v3;
  if (f32) {
    const float4 vv = *(const float4*)((const float*)v + i);
    v0 = vv.x; v1 = vv.y; v2 = vv.z; v3 = vv.w;
  } else {
    const uint2 vr = *(const uint2*)((const unsigned short*)v + i);
    v0 = bf2f((unsigned short)(vr.x & 0xffffu));
    v1 = bf2f((unsigned short)(vr.x >> 16));
    v2 = bf2f((unsigned short)(vr.y & 0xffffu));
    v3 = bf2f((unsigned short)(vr.y >> 16));
  }
  const uint2 Fr = *(const uint2*)&F[i];
  const uint2 Or = *(const uint2*)&O[i];
  const uint2 Tr = *(const uint2*)&T[i];
  float4 o;
  o.x = bf2f((unsigned short)(Fr.x & 0xffffu)) * v0 + bf2f((unsigned short)(Or.x & 0xffffu)) * bf2f((unsigned short)(Tr.x & 0xffffu));
  o.y = bf2f((unsigned short)(Fr.x >> 16))     * v1 + bf2f((unsigned short)(Or.x >> 16))     * bf2f((unsigned short)(Tr.x >> 16));
  o.z = bf2f((unsigned short)(Fr.y & 0xffffu)) * v2 + bf2f((unsigned short)(Or.y & 0xffffu)) * bf2f((unsigned short)(Tr.y & 0xffffu));
  o.w = bf2f((unsigned short)(Fr.y >> 16))     * v3 + bf2f((unsigned short)(Or.y >> 16))     * bf2f((unsigned short)(Tr.y >> 16));
  *(float4*)&out[V_OFF + i] = o;
}

// ---------------- H = (1-k)*hv + k*hx  (fp32 to d_out) ----------------
__global__ __launch_bounds__(256) void h_combine(
    const unsigned short* __restrict__ kk, const unsigned short* __restrict__ hv,
    const unsigned short* __restrict__ hx, float* __restrict__ Hout) {
  const int i = (blockIdx.x * 256 + threadIdx.x) * 4;
  const uint2 kr = *(const uint2*)&kk[i];
  const uint2 vr = *(const uint2*)&hv[i];
  const uint2 xr = *(const uint2*)&hx[i];
  const float k0 = bf2f((unsigned short)(kr.x & 0xffffu)), k1 = bf2f((unsigned short)(kr.x >> 16));
  const float k2 = bf2f((unsigned short)(kr.y & 0xffffu)), k3 = bf2f((unsigned short)(kr.y >> 16));
  const float hv0 = bf2f((unsigned short)(vr.x & 0xffffu)), hv1 = bf2f((unsigned short)(vr.x >> 16));
  const float hv2 = bf2f((unsigned short)(vr.y & 0xffffu)), hv3 = bf2f((unsigned short)(vr.y >> 16));
  const float hx0 = bf2f((unsigned short)(xr.x & 0xffffu)), hx1 = bf2f((unsigned short)(xr.x >> 16));
  const float hx2 = bf2f((unsigned short)(xr.y & 0xffffu)), hx3 = bf2f((unsigned short)(xr.y >> 16));
  float4 o;
  o.x = (1.f - k0) * hv0 + k0 * hx0;
  o.y = (1.f - k1) * hv1 + k1 * hx1;
  o.z = (1.f - k2) * hv2 + k2 * hx2;
  o.w = (1.f - k3) * hv3 + k3 * hx3;
  *(float4*)&Hout[i] = o;
}

extern "C" void kernel_launch(void* const* d_in, const int* in_sizes, int n_in,
                              void* d_out, int out_size, void* d_ws, size_t ws_size,
                              hipStream_t stream) {
  const void* X   = d_in[0];
  const void* S   = d_in[1];
  const void* h   = d_in[2];
  const void* v   = d_in[3];
  const void* b_a = d_in[6];
  const void* v_a = d_in[7];
  const void* b_f = d_in[10];
  const void* b_o = d_in[13];
  const void* b_t = d_in[16];
  const void* b_k = d_in[20];
  const void* b_s = d_in[23];
  const void* b_v = d_in[26];

  float* out = (float*)d_out;  // fp32 output (H | P | V)
  float* out_V = out + V_OFF;

  char* ws = (char*)d_ws;
  int* flag = (int*)ws;
  size_t off = 256;

  const int widx[15] = {4, 5, 8, 9, 11, 12, 14, 15, 17, 18, 19, 21, 22, 24, 25};
  const int wK[15]   = {256, 256, 256, 256, 256, 256, 256, 256, 512, 256, 256, 512, 256, 256, 256};
  TJobs tj;
  unsigned short* wt[15];
  for (int i = 0; i < 15; ++i) {
    wt[i] = (unsigned short*)(ws + off);
    off += (size_t)wK[i] * 256 * 2;
    tj.src[i] = d_in[widx[i]];
    tj.dst[i] = wt[i];
    tj.K[i] = wK[i];
  }
  const unsigned short *WsaT = wt[0], *WhaT = wt[1], *WfT = wt[2], *WhfT = wt[3],
                       *WoT = wt[4], *WhoT = wt[5], *WtT = wt[6], *WhtT = wt[7],
                       *WkT = wt[8], *WhkT = wt[9], *WvkT = wt[10], *WsT = wt[11],
                       *WhsT = wt[12], *WvT = wt[13], *WhvT = wt[14];
  off = (off + 255) & ~(size_t)255;
  const size_t BS = (size_t)B_N * 256 * 2;  // bf16 [8192,256] = 4 MB
  unsigned short* hWa   = (unsigned short*)(ws + off); off += BS;
  float* scores         = (float*)(ws + off);          off += (size_t)R_N * sizeof(float);
  unsigned short* text  = (unsigned short*)(ws + off); off += BS;
  unsigned short* Fb    = (unsigned short*)(ws + off); off += BS;
  unsigned short* Ob    = (unsigned short*)(ws + off); off += BS;
  unsigned short* Tb    = (unsigned short*)(ws + off); off += BS;
  unsigned short* kpre  = (unsigned short*)(ws + off); off += BS;
  unsigned short* hx    = (unsigned short*)(ws + off); off += BS;
  unsigned short* hvpre = (unsigned short*)(ws + off); off += BS;

  probe_dtype<<<1, 64, 0, stream>>>(X, flag);
  transpose_weights<<<dim3(16, 32, 15), 256, 0, stream>>>(tj, flag);

  // Launch A: hWa, kpre, hx, hvpre
  GJobs jA;
  for (int i = 0; i < 4; ++i) jA.j[i] = GJob{};
  jA.j[0].A[0] = h;  jA.j[0].atag[0] = 2; jA.j[0].Wt[0] = WhaT; jA.j[0].K[0] = 256;
  jA.j[0].bias = b_a; jA.j[0].out = hWa; jA.j[0].act = 0;
  jA.j[1].A[0] = X;  jA.j[1].atag[0] = 2; jA.j[1].Wt[0] = WkT;  jA.j[1].K[0] = 512;
  jA.j[1].A[1] = h;  jA.j[1].atag[1] = 2; jA.j[1].Wt[1] = WhkT; jA.j[1].K[1] = 256;
  jA.j[1].bias = b_k; jA.j[1].out = kpre; jA.j[1].act = 0;
  jA.j[2].A[0] = X;  jA.j[2].atag[0] = 2; jA.j[2].Wt[0] = WsT;  jA.j[2].K[0] = 512;
  jA.j[2].A[1] = h;  jA.j[2].atag[1] = 2; jA.j[2].Wt[1] = WhsT; jA.j[2].K[1] = 256;
  jA.j[2].bias = b_s; jA.j[2].out = hx; jA.j[2].act = 2;
  jA.j[3].A[0] = h;  jA.j[3].atag[0] = 2; jA.j[3].Wt[0] = WhvT; jA.j[3].K[0] = 256;
  jA.j[3].bias = b_v; jA.j[3].out = hvpre; jA.j[3].act = 0;
  gemm_small<<<dim3(128, 2, 4), 256, 0, stream>>>(jA, flag);

  attn_scores<<<dim3(R_N / 128), 512, 0, stream>>>(S, WsaT, hWa, v_a, scores, flag);
  softmax_text<<<dim3(B_N / 4), 256, 0, stream>>>(scores, S, out, text, flag);

  // Launch B: F, O, T
  GJobs jB;
  for (int i = 0; i < 4; ++i) jB.j[i] = GJob{};
  jB.j[0].A[0] = text; jB.j[0].atag[0] = 0; jB.j[0].Wt[0] = WfT;  jB.j[0].K[0] = 256;
  jB.j[0].A[1] = h;    jB.j[0].atag[1] = 2; jB.j[0].Wt[1] = WhfT; jB.j[0].K[1] = 256;
  jB.j[0].bias = b_f; jB.j[0].out = Fb; jB.j[0].act = 1;
  jB.j[1].A[0] = text; jB.j[1].atag[0] = 0; jB.j[1].Wt[0] = WoT;  jB.j[1].K[0] = 256;
  jB.j[1].A[1] = h;    jB.j[1].atag[1] = 2; jB.j[1].Wt[1] = WhoT; jB.j[1].K[1] = 256;
  jB.j[1].bias = b_o; jB.j[1].out = Ob; jB.j[1].act = 1;
  jB.j[2].A[0] = text; jB.j[2].atag[0] = 0; jB.j[2].Wt[0] = WtT;  jB.j[2].K[0] = 256;
  jB.j[2].A[1] = h;    jB.j[2].atag[1] = 2; jB.j[2].Wt[1] = WhtT; jB.j[2].K[1] = 256;
  jB.j[2].bias = b_t; jB.j[2].out = Tb; jB.j[2].act = 2;
  gemm_small<<<dim3(128, 2, 3), 256, 0, stream>>>(jB, flag);

  v_combine<<<dim3(B_N * 256 / 1024), 256, 0, stream>>>(Fb, Ob, Tb, v, out, flag);

  // Launch C: k = sigmoid(V@W_vk + kpre), hv = tanh(V@W_v + hvpre); V is fp32 in d_out
  GJobs jC;
  for (int i = 0; i < 4; ++i) jC.j[i] = GJob{};
  jC.j[0].A[0] = out_V; jC.j[0].atag[0] = 1; jC.j[0].Wt[0] = WvkT; jC.j[0].K[0] = 256;
  jC.j[0].add = kpre; jC.j[0].out = kpre; jC.j[0].act = 1;
  jC.j[1].A[0] = out_V; jC.j[1].atag[0] = 1; jC.j[1].Wt[0] = WvT;  jC.j[1].K[0] = 256;
  jC.j[1].add = hvpre; jC.j[1].out = hvpre; jC.j[1].act = 2;
  gemm_small<<<dim3(128, 2, 2), 256, 0, stream>>>(jC, flag);

  h_combine<<<dim3(B_N * 256 / 1024), 256, 0, stream>>>(kpre, hvpre, hx, out);
}

// Round 4
// 858.185 us; speedup vs baseline: 1.0769x; 1.0062x over previous
//
#include <hip/hip_runtime.h>
#include <cstddef>

typedef __bf16 bf16x8 __attribute__((ext_vector_type(8)));
typedef unsigned short u16x8 __attribute__((ext_vector_type(8)));
typedef float f32x4 __attribute__((ext_vector_type(4)));

#define B_N 8192
#define M_N 50
#define R_N (B_N * M_N)   // 409600
#define P_OFF ((size_t)B_N * 256)
#define V_OFF ((size_t)B_N * 256 + (size_t)B_N * 50)

__device__ __forceinline__ float bf2f(unsigned short u) {
  return __uint_as_float(((unsigned int)u) << 16);
}
__device__ __forceinline__ unsigned short f2bf(float f) {
  unsigned int u = __float_as_uint(f);
  u += 0x7fffu + ((u >> 16) & 1u);
  return (unsigned short)(u >> 16);
}
__device__ __forceinline__ float fsig(float x) { return 1.f / (1.f + __expf(-x)); }
__device__ __forceinline__ float ftanh(float x) {
  float e = __expf(2.f * x);
  return 1.f - 2.f / (e + 1.f);
}

// scalar adaptive load of external input
__device__ __forceinline__ float ld_ext(const void* p, size_t i, bool f32) {
  return f32 ? ((const float*)p)[i] : bf2f(((const unsigned short*)p)[i]);
}

// async global -> LDS, 16 bytes per lane; lds dest is wave-uniform base + lane*16
__device__ __forceinline__ void gload_lds16(const void* g, void* l) {
  __builtin_amdgcn_global_load_lds(
      (const __attribute__((address_space(1))) unsigned int*)g,
      (__attribute__((address_space(3))) unsigned int*)l, 16, 0, 0);
}

// XOR bank swizzle, PROPER INVOLUTION (source bits 7..9, dest bits 4..6 disjoint):
// for 64B-row layouts this spreads row groups across 16B slots; same map applied
// on the staging (source-address) side and the ds_read side.
__device__ __forceinline__ unsigned swz(unsigned a) {
  return a ^ (((a >> 7) & 7u) << 4);
}

// ---------------- dtype probe on X ----------------
__global__ void probe_dtype(const void* __restrict__ X, int* __restrict__ flag) {
  const int lane = threadIdx.x;  // 64 threads
  const unsigned short u = ((const unsigned short*)X)[lane * 2];
  const int e = (u >> 7) & 0xff;
  const bool plausible = (e >= 110 && e <= 144) || (u == 0);
  const unsigned long long m = __ballot(plausible);
  if (lane == 0) *flag = (__popcll(m) < 32) ? 1 : 0;  // 1 => f32 inputs
}

// ---------------- weight transpose: W[K,256] -> WT[256,K] bf16 ----------------
struct TJobs {
  const void* src[15];
  unsigned short* dst[15];
  int K[15];
};

__global__ __launch_bounds__(256) void transpose_weights(TJobs jobs, const int* __restrict__ flagp) {
  const bool f32 = *flagp != 0;
  const int z = blockIdx.z;
  const void* __restrict__ src = jobs.src[z];
  unsigned short* __restrict__ dst = jobs.dst[z];
  const int K = jobs.K[z];
  const int k0 = blockIdx.y * 16;
  if (k0 >= K) return;
  const int n0 = blockIdx.x * 16;
  __shared__ __align__(16) unsigned short tile[16][17];
  const int tx = threadIdx.x & 15, ty = threadIdx.x >> 4;
  const size_t sidx = (size_t)(k0 + ty) * 256 + n0 + tx;
  tile[ty][tx] = f32 ? f2bf(((const float*)src)[sidx]) : ((const unsigned short*)src)[sidx];
  __syncthreads();
  dst[(size_t)(n0 + ty) * K + k0 + tx] = tile[tx][ty];
}

// ---------------- generic small GEMM (2-phase pipelined) ----------------
struct GJob {
  const void* A[3];             // [8192, K_p] row-major
  const unsigned short* Wt[3];  // [256, K_p] bf16 transposed weight (internal)
  int K[3];                     // 0 terminates
  int atag[3];                  // 0 = internal bf16, 1 = always f32, 2 = external (follow flag)
  const void* bias;             // [256] external or null
  const unsigned short* add;    // [8192,256] bf16 internal or null
  unsigned short* out;          // [8192,256] bf16 internal
  int act;                      // 0 none, 1 sigmoid, 2 tanh
};
struct GJobs { GJob j[4]; };

__global__ __launch_bounds__(256) void gemm_small(GJobs jobs, const int* __restrict__ flagp) {
  const bool flag32 = *flagp != 0;
  const GJob job = jobs.j[blockIdx.z];
  const int tid = threadIdx.x;
  const int row0 = blockIdx.x * 64;
  const int col0 = blockIdx.y * 128;
  __shared__ __align__(16) unsigned short As[2][64][40];
  __shared__ __align__(16) unsigned short Ws[2][128][40];

  f32x4 acc[2][4];
#pragma unroll
  for (int i = 0; i < 2; ++i)
#pragma unroll
    for (int j = 0; j < 4; ++j) acc[i][j] = (f32x4){0.f, 0.f, 0.f, 0.f};

  const int wave = tid >> 6, lane = tid & 63;
  const int wr = wave >> 1, wc = wave & 1;
  const int quad = lane >> 4, l16 = lane & 15;

  // flatten segments
  const void* Aseg[3]; const unsigned short* Wseg[3]; int Kseg[3]; bool Fseg[3];
  int nseg = 0, nt = 0, sbeg[4];
  sbeg[0] = 0;
  for (int p = 0; p < 3; ++p) {
    if (job.K[p] == 0) break;
    Aseg[nseg] = job.A[p]; Wseg[nseg] = job.Wt[p]; Kseg[nseg] = job.K[p];
    Fseg[nseg] = (job.atag[p] == 1) || (job.atag[p] == 2 && flag32);
    nt += job.K[p] / 32;
    ++nseg; sbeg[nseg] = nt;
  }

  const int rA = tid >> 2, cA = (tid & 3) * 8;   // A chunk: row rA, col cA (8 elem)
  const int rW = tid >> 2, cW = (tid & 3) * 8;   // W chunks: rows rW and rW+64

  uint4 pa, pw0, pw1;
  float4 fa, fb;
  bool pf32 = false;

  auto issue = [&](int t) {
    int s = 0;
    while (t >= sbeg[s + 1]) ++s;
    const int k0 = (t - sbeg[s]) * 32;
    const int Kp = Kseg[s];
    pf32 = Fseg[s];
    if (pf32) {
      const float* fp = (const float*)Aseg[s] + (size_t)(row0 + rA) * Kp + k0 + cA;
      fa = *(const float4*)fp;
      fb = *(const float4*)(fp + 4);
    } else {
      pa = *(const uint4*)((const unsigned short*)Aseg[s] + (size_t)(row0 + rA) * Kp + k0 + cA);
    }
    pw0 = *(const uint4*)&Wseg[s][(size_t)(col0 + rW) * Kp + k0 + cW];
    pw1 = *(const uint4*)&Wseg[s][(size_t)(col0 + rW + 64) * Kp + k0 + cW];
  };
  auto commit = [&](int buf) {
    if (pf32) {
      u16x8 v;
      v[0] = f2bf(fa.x); v[1] = f2bf(fa.y); v[2] = f2bf(fa.z); v[3] = f2bf(fa.w);
      v[4] = f2bf(fb.x); v[5] = f2bf(fb.y); v[6] = f2bf(fb.z); v[7] = f2bf(fb.w);
      *(u16x8*)&As[buf][rA][cA] = v;
    } else {
      *(uint4*)&As[buf][rA][cA] = pa;
    }
    *(uint4*)&Ws[buf][rW][cW] = pw0;
    *(uint4*)&Ws[buf][rW + 64][cW] = pw1;
  };

  issue(0);
  commit(0);
  __syncthreads();

  int buf = 0;
  for (int t = 0; t < nt; ++t) {
    if (t + 1 < nt) issue(t + 1);   // global loads for next tile in flight over compute
    bf16x8 af[2], bfr[4];
#pragma unroll
    for (int mi = 0; mi < 2; ++mi)
      af[mi] = *(const bf16x8*)&As[buf][wr * 32 + mi * 16 + l16][quad * 8];
#pragma unroll
    for (int ni = 0; ni < 4; ++ni)
      bfr[ni] = *(const bf16x8*)&Ws[buf][wc * 64 + ni * 16 + l16][quad * 8];
#pragma unroll
    for (int mi = 0; mi < 2; ++mi)
#pragma unroll
      for (int ni = 0; ni < 4; ++ni)
        acc[mi][ni] = __builtin_amdgcn_mfma_f32_16x16x32_bf16(af[mi], bfr[ni], acc[mi][ni], 0, 0, 0);
    if (t + 1 < nt) commit(buf ^ 1);
    __syncthreads();
    buf ^= 1;
  }

#pragma unroll
  for (int mi = 0; mi < 2; ++mi) {
#pragma unroll
    for (int ni = 0; ni < 4; ++ni) {
      const int col = col0 + wc * 64 + ni * 16 + l16;
      const float bias = job.bias ? ld_ext(job.bias, col, flag32) : 0.f;
      const int rowb = row0 + wr * 32 + mi * 16 + quad * 4;
#pragma unroll
      for (int r = 0; r < 4; ++r) {
        float v = acc[mi][ni][r] + bias;
        const size_t idx = (size_t)(rowb + r) * 256 + col;
        if (job.add) v += bf2f(job.add[idx]);
        if (job.act == 1) v = fsig(v);
        else if (job.act == 2) v = ftanh(v);
        job.out[idx] = f2bf(v);
      }
    }
  }
}

// ---------------- fused attention: scores + softmax + text, one block per batch ----
// S panel (50 rows, padded to 64 w/ row-clamp) staged slice-major into persistent
// LDS while the K-loop runs; W_sa streamed double-buffered; softmax + P.S from LDS.
// Eliminates the second global pass over S and the scores round-trip.
__global__ __launch_bounds__(512, 4) void attn_fused(
    const void* __restrict__ S,
    const unsigned short* __restrict__ WsaT,
    const unsigned short* __restrict__ hWa,   // bf16 [8192,256]
    const void* __restrict__ v_a,
    float* __restrict__ out,                  // fp32 output base (P at P_OFF)
    unsigned short* __restrict__ text,        // internal bf16 [8192,256]
    const int* __restrict__ flagp) {
  const bool f32 = *flagp != 0;
  const int tid = threadIdx.x;
  const int b0 = blockIdx.x;                  // batch index
  const size_t srow0 = (size_t)b0 * 50;

  // slice-major: slice t (k in [t*32,t*32+32)) occupies phys [t*4096, t*4096+4096);
  // within a slice, logical byte = row*64 + (k-in-slice)*2, phys = swz(logical).
  __shared__ __align__(128) unsigned short Sl[8 * 64 * 32];    // 32 KB, persistent
  __shared__ __align__(128) unsigned short Wl[2 * 256 * 32];   // 32 KB, dbuf
  __shared__ float hWs[256];
  __shared__ float vas[256];
  __shared__ __align__(16) float red[64][4];
  __shared__ float Pl[64];

  const int wave = tid >> 6, lane = tid & 63;
  const int wr = wave >> 2, wc = wave & 3;     // 2 x 4 wave grid (64 rows x 256 cols)
  const int quad = lane >> 4, l16 = lane & 15;

  // S staging geometry: threads 0..255 cover phys chunk tid*16 of each slice;
  // phys chunk c holds logical chunk swz(c) (involution => read side uses swz too).
  const unsigned cS = (unsigned)tid * 16;
  const unsigned lS = swz(cS);
  const unsigned rowS = lS >> 6;
  const unsigned eS = (lS & 63) >> 1;                       // k-elem offset (mult of 8)
  const size_t gS = (srow0 + (rowS < 50 ? rowS : 49)) * 256 + eS;  // clamped, + t*32

  // W staging geometry: 2 chunks/thread per 16KB slice (phys tid*16 and +8192).
  const unsigned c0 = (unsigned)tid * 16, c1 = c0 + 8192;
  const unsigned l0 = swz(c0), l1 = swz(c1);
  const size_t gW0 = (size_t)(l0 >> 6) * 256 + ((l0 & 63) >> 1);
  const size_t gW1 = (size_t)(l1 >> 6) * 256 + ((l1 & 63) >> 1);

  auto stageS = [&](int t) {
    if (wave < 4) {
      if (f32) {
        const float* fp = (const float*)S + gS + t * 32;
        const float4 a = *(const float4*)fp;
        const float4 b = *(const float4*)(fp + 4);
        u16x8 v;
        v[0] = f2bf(a.x); v[1] = f2bf(a.y); v[2] = f2bf(a.z); v[3] = f2bf(a.w);
        v[4] = f2bf(b.x); v[5] = f2bf(b.y); v[6] = f2bf(b.z); v[7] = f2bf(b.w);
        *(u16x8*)((char*)Sl + t * 4096 + cS) = v;
      } else {
        gload_lds16((const unsigned short*)S + gS + t * 32,
                    (char*)Sl + t * 4096 + (wave << 10));
      }
    }
  };
  auto stageW = [&](int t, int buf) {
    char* base = (char*)Wl + buf * 16384;
    gload_lds16(WsaT + gW0 + t * 32, base + (wave << 10));
    gload_lds16(WsaT + gW1 + t * 32, base + 8192 + (wave << 10));
  };

  f32x4 acc[2][4];
#pragma unroll
  for (int i = 0; i < 2; ++i)
#pragma unroll
    for (int j = 0; j < 4; ++j) acc[i][j] = (f32x4){0.f, 0.f, 0.f, 0.f};

  stageS(0);
  stageW(0, 0);
  if (tid < 256) {
    hWs[tid] = bf2f(hWa[(size_t)b0 * 256 + tid]);
    vas[tid] = ld_ext(v_a, tid, f32);
  }
  __syncthreads();

  for (int t = 0; t < 8; ++t) {
    if (t < 7) { stageS(t + 1); stageW(t + 1, (t + 1) & 1); }
    const char* sl = (const char*)Sl + t * 4096;
    const char* wl = (const char*)Wl + (t & 1) * 16384;
    bf16x8 af[2], bfr[4];
#pragma unroll
    for (int mi = 0; mi < 2; ++mi)
      af[mi] = *(const bf16x8*)(sl + swz((unsigned)(wr * 32 + mi * 16 + l16) * 64 + quad * 16));
#pragma unroll
    for (int ni = 0; ni < 4; ++ni)
      bfr[ni] = *(const bf16x8*)(wl + swz((unsigned)(wc * 64 + ni * 16 + l16) * 64 + quad * 16));
#pragma unroll
    for (int mi = 0; mi < 2; ++mi)
#pragma unroll
      for (int ni = 0; ni < 4; ++ni)
        acc[mi][ni] = __builtin_amdgcn_mfma_f32_16x16x32_bf16(af[mi], bfr[ni], acc[mi][ni], 0, 0, 0);
    __syncthreads();
  }

  // scores epilogue: s[row] = sum_col tanh(acc + hW[col]) * v_a[col]
#pragma unroll
  for (int mi = 0; mi < 2; ++mi) {
#pragma unroll
    for (int r = 0; r < 4; ++r) {
      const int rl = wr * 32 + mi * 16 + quad * 4 + r;
      float s = 0.f;
#pragma unroll
      for (int ni = 0; ni < 4; ++ni) {
        const int col = wc * 64 + ni * 16 + l16;
        s += ftanh(acc[mi][ni][r] + hWs[col]) * vas[col];
      }
      s += __shfl_xor(s, 1);
      s += __shfl_xor(s, 2);
      s += __shfl_xor(s, 4);
      s += __shfl_xor(s, 8);
      if (l16 == 0) red[rl][wc] = s;
    }
  }
  __syncthreads();

  // softmax over the 50 scores (wave 0)
  if (tid < 64) {
    const float4 rr = *(const float4*)&red[tid][0];
    const float sc = rr.x + rr.y + rr.z + rr.w;
    float sv = (tid < 50) ? sc : -1e30f;
    float mx = sv;
#pragma unroll
    for (int off = 32; off > 0; off >>= 1) mx = fmaxf(mx, __shfl_xor(mx, off));
    float e = (tid < 50) ? __expf(sv - mx) : 0.f;
    float sum = e;
#pragma unroll
    for (int off = 32; off > 0; off >>= 1) sum += __shfl_xor(sum, off);
    const float p = e / sum;
    Pl[tid] = p;
    if (tid < 50) out[P_OFF + (size_t)b0 * 50 + tid] = p;
  }
  __syncthreads();

  // text[c] = sum_m P[m] * S[m][c], read back from the persistent LDS panel
  if (tid < 256) {
    const int t = tid >> 5;                    // k-slice holding col c
    const unsigned bc = (unsigned)(tid & 31) * 2;
    float a = 0.f;
#pragma unroll 10
    for (int m = 0; m < 50; ++m) {
      const unsigned off = (unsigned)t * 4096 + swz((unsigned)m * 64 + bc);
      a += Pl[m] * bf2f(*(const unsigned short*)((const char*)Sl + off));
    }
    text[(size_t)b0 * 256 + tid] = f2bf(a);
  }
}

// ---------------- V = F*v + O*T  (fp32 to d_out) ----------------
__global__ __launch_bounds__(256) void v_combine(
    const unsigned short* __restrict__ F, const unsigned short* __restrict__ O,
    const unsigned short* __restrict__ T,
    const void* __restrict__ v, float* __restrict__ out,
    const int* __restrict__ flagp) {
  const bool f32 = *flagp != 0;
  const int i = (blockIdx.x * 256 + threadIdx.x) * 4;
  float v0, v1, v2, v3;
  if (f32) {
    const float4 vv = *(const float4*)((const float*)v + i);
    v0 = vv.x; v1 = vv.y; v2 = vv.z; v3 = vv.w;
  } else {
    const uint2 vr = *(const uint2*)((const unsigned short*)v + i);
    v0 = bf2f((unsigned short)(vr.x & 0xffffu));
    v1 = bf2f((unsigned short)(vr.x >> 16));
    v2 = bf2f((unsigned short)(vr.y & 0xffffu));
    v3 = bf2f((unsigned short)(vr.y >> 16));
  }
  const uint2 Fr = *(const uint2*)&F[i];
  const uint2 Or = *(const uint2*)&O[i];
  const uint2 Tr = *(const uint2*)&T[i];
  float4 o;
  o.x = bf2f((unsigned short)(Fr.x & 0xffffu)) * v0 + bf2f((unsigned short)(Or.x & 0xffffu)) * bf2f((unsigned short)(Tr.x & 0xffffu));
  o.y = bf2f((unsigned short)(Fr.x >> 16))     * v1 + bf2f((unsigned short)(Or.x >> 16))     * bf2f((unsigned short)(Tr.x >> 16));
  o.z = bf2f((unsigned short)(Fr.y & 0xffffu)) * v2 + bf2f((unsigned short)(Or.y & 0xffffu)) * bf2f((unsigned short)(Tr.y & 0xffffu));
  o.w = bf2f((unsigned short)(Fr.y >> 16))     * v3 + bf2f((unsigned short)(Or.y >> 16))     * bf2f((unsigned short)(Tr.y >> 16));
  *(float4*)&out[V_OFF + i] = o;
}

// ---------------- H = (1-k)*hv + k*hx  (fp32 to d_out) ----------------
__global__ __launch_bounds__(256) void h_combine(
    const unsigned short* __restrict__ kk, const unsigned short* __restrict__ hv,
    const unsigned short* __restrict__ hx, float* __restrict__ Hout) {
  const int i = (blockIdx.x * 256 + threadIdx.x) * 4;
  const uint2 kr = *(const uint2*)&kk[i];
  const uint2 vr = *(const uint2*)&hv[i];
  const uint2 xr = *(const uint2*)&hx[i];
  const float k0 = bf2f((unsigned short)(kr.x & 0xffffu)), k1 = bf2f((unsigned short)(kr.x >> 16));
  const float k2 = bf2f((unsigned short)(kr.y & 0xffffu)), k3 = bf2f((unsigned short)(kr.y >> 16));
  const float hv0 = bf2f((unsigned short)(vr.x & 0xffffu)), hv1 = bf2f((unsigned short)(vr.x >> 16));
  const float hv2 = bf2f((unsigned short)(vr.y & 0xffffu)), hv3 = bf2f((unsigned short)(vr.y >> 16));
  const float hx0 = bf2f((unsigned short)(xr.x & 0xffffu)), hx1 = bf2f((unsigned short)(xr.x >> 16));
  const float hx2 = bf2f((unsigned short)(xr.y & 0xffffu)), hx3 = bf2f((unsigned short)(xr.y >> 16));
  float4 o;
  o.x = (1.f - k0) * hv0 + k0 * hx0;
  o.y = (1.f - k1) * hv1 + k1 * hx1;
  o.z = (1.f - k2) * hv2 + k2 * hx2;
  o.w = (1.f - k3) * hv3 + k3 * hx3;
  *(float4*)&Hout[i] = o;
}

extern "C" void kernel_launch(void* const* d_in, const int* in_sizes, int n_in,
                              void* d_out, int out_size, void* d_ws, size_t ws_size,
                              hipStream_t stream) {
  const void* X   = d_in[0];
  const void* S   = d_in[1];
  const void* h   = d_in[2];
  const void* v   = d_in[3];
  const void* b_a = d_in[6];
  const void* v_a = d_in[7];
  const void* b_f = d_in[10];
  const void* b_o = d_in[13];
  const void* b_t = d_in[16];
  const void* b_k = d_in[20];
  const void* b_s = d_in[23];
  const void* b_v = d_in[26];

  float* out = (float*)d_out;  // fp32 output (H | P | V)
  float* out_V = out + V_OFF;

  char* ws = (char*)d_ws;
  int* flag = (int*)ws;
  size_t off = 256;

  const int widx[15] = {4, 5, 8, 9, 11, 12, 14, 15, 17, 18, 19, 21, 22, 24, 25};
  const int wK[15]   = {256, 256, 256, 256, 256, 256, 256, 256, 512, 256, 256, 512, 256, 256, 256};
  TJobs tj;
  unsigned short* wt[15];
  for (int i = 0; i < 15; ++i) {
    wt[i] = (unsigned short*)(ws + off);
    off += (size_t)wK[i] * 256 * 2;
    tj.src[i] = d_in[widx[i]];
    tj.dst[i] = wt[i];
    tj.K[i] = wK[i];
  }
  const unsigned short *WsaT = wt[0], *WhaT = wt[1], *WfT = wt[2], *WhfT = wt[3],
                       *WoT = wt[4], *WhoT = wt[5], *WtT = wt[6], *WhtT = wt[7],
                       *WkT = wt[8], *WhkT = wt[9], *WvkT = wt[10], *WsT = wt[11],
                       *WhsT = wt[12], *WvT = wt[13], *WhvT = wt[14];
  off = (off + 255) & ~(size_t)255;
  const size_t BS = (size_t)B_N * 256 * 2;  // bf16 [8192,256] = 4 MB
  unsigned short* hWa   = (unsigned short*)(ws + off); off += BS;
  unsigned short* text  = (unsigned short*)(ws + off); off += BS;
  unsigned short* Fb    = (unsigned short*)(ws + off); off += BS;
  unsigned short* Ob    = (unsigned short*)(ws + off); off += BS;
  unsigned short* Tb    = (unsigned short*)(ws + off); off += BS;
  unsigned short* kpre  = (unsigned short*)(ws + off); off += BS;
  unsigned short* hx    = (unsigned short*)(ws + off); off += BS;
  unsigned short* hvpre = (unsigned short*)(ws + off); off += BS;

  probe_dtype<<<1, 64, 0, stream>>>(X, flag);
  transpose_weights<<<dim3(16, 32, 15), 256, 0, stream>>>(tj, flag);

  // Launch A: hWa, kpre, hx, hvpre
  GJobs jA;
  for (int i = 0; i < 4; ++i) jA.j[i] = GJob{};
  jA.j[0].A[0] = h;  jA.j[0].atag[0] = 2; jA.j[0].Wt[0] = WhaT; jA.j[0].K[0] = 256;
  jA.j[0].bias = b_a; jA.j[0].out = hWa; jA.j[0].act = 0;
  jA.j[1].A[0] = X;  jA.j[1].atag[0] = 2; jA.j[1].Wt[0] = WkT;  jA.j[1].K[0] = 512;
  jA.j[1].A[1] = h;  jA.j[1].atag[1] = 2; jA.j[1].Wt[1] = WhkT; jA.j[1].K[1] = 256;
  jA.j[1].bias = b_k; jA.j[1].out = kpre; jA.j[1].act = 0;
  jA.j[2].A[0] = X;  jA.j[2].atag[0] = 2; jA.j[2].Wt[0] = WsT;  jA.j[2].K[0] = 512;
  jA.j[2].A[1] = h;  jA.j[2].atag[1] = 2; jA.j[2].Wt[1] = WhsT; jA.j[2].K[1] = 256;
  jA.j[2].bias = b_s; jA.j[2].out = hx; jA.j[2].act = 2;
  jA.j[3].A[0] = h;  jA.j[3].atag[0] = 2; jA.j[3].Wt[0] = WhvT; jA.j[3].K[0] = 256;
  jA.j[3].bias = b_v; jA.j[3].out = hvpre; jA.j[3].act = 0;
  gemm_small<<<dim3(128, 2, 4), 256, 0, stream>>>(jA, flag);

  attn_fused<<<dim3(B_N), 512, 0, stream>>>(S, WsaT, hWa, v_a, out, text, flag);

  // Launch B: F, O, T
  GJobs jB;
  for (int i = 0; i < 4; ++i) jB.j[i] = GJob{};
  jB.j[0].A[0] = text; jB.j[0].atag[0] = 0; jB.j[0].Wt[0] = WfT;  jB.j[0].K[0] = 256;
  jB.j[0].A[1] = h;    jB.j[0].atag[1] = 2; jB.j[0].Wt[1] = WhfT; jB.j[0].K[1] = 256;
  jB.j[0].bias = b_f; jB.j[0].out = Fb; jB.j[0].act = 1;
  jB.j[1].A[0] = text; jB.j[1].atag[0] = 0; jB.j[1].Wt[0] = WoT;  jB.j[1].K[0] = 256;
  jB.j[1].A[1] = h;    jB.j[1].atag[1] = 2; jB.j[1].Wt[1] = WhoT; jB.j[1].K[1] = 256;
  jB.j[1].bias = b_o; jB.j[1].out = Ob; jB.j[1].act = 1;
  jB.j[2].A[0] = text; jB.j[2].atag[0] = 0; jB.j[2].Wt[0] = WtT;  jB.j[2].K[0] = 256;
  jB.j[2].A[1] = h;    jB.j[2].atag[1] = 2; jB.j[2].Wt[1] = WhtT; jB.j[2].K[1] = 256;
  jB.j[2].bias = b_t; jB.j[2].out = Tb; jB.j[2].act = 2;
  gemm_small<<<dim3(128, 2, 3), 256, 0, stream>>>(jB, flag);

  v_combine<<<dim3(B_N * 256 / 1024), 256, 0, stream>>>(Fb, Ob, Tb, v, out, flag);

  // Launch C: k = sigmoid(V@W_vk + kpre), hv = tanh(V@W_v + hvpre); V is fp32 in d_out
  GJobs jC;
  for (int i = 0; i < 4; ++i) jC.j[i] = GJob{};
  jC.j[0].A[0] = out_V; jC.j[0].atag[0] = 1; jC.j[0].Wt[0] = WvkT; jC.j[0].K[0] = 256;
  jC.j[0].add = kpre; jC.j[0].out = kpre; jC.j[0].act = 1;
  jC.j[1].A[0] = out_V; jC.j[1].atag[0] = 1; jC.j[1].Wt[0] = WvT;  jC.j[1].K[0] = 256;
  jC.j[1].add = hvpre; jC.j[1].out = hvpre; jC.j[1].act = 2;
  gemm_small<<<dim3(128, 2, 2), 256, 0, stream>>>(jC, flag);

  h_combine<<<dim3(B_N * 256 / 1024), 256, 0, stream>>>(kpre, hvpre, hx, out);
}